// Round 18
// baseline (116380.933 us; speedup 1.0000x reference)
//
#include <hip/hip_runtime.h>
#include <stdint.h>

#define NBATCH  32
#define NPTS    131072
#define NPOINTS 4096
#define BPB     32           // blocks per batch -> grid = 1024 = 4 blocks/CU (co-resident, forced)
#define TPB     512          // threads per block
#define PPT     8            // points per thread = NPTS/BPB/TPB -> 32 array VGPRs
#define PPB     (NPTS / BPB) // 4096 points per block

typedef unsigned long long u64;
typedef unsigned int u32;

#define SLOT_STRIDE 8        // u64s -> 64 B between slots

// Slot (batch, parity, block): word0 = [60:49] it+1 | [48:17] f32 dist bits | [16:0] 131071-gi
//                              word1 = (ybits<<32)|xbits   word2 = zbits
// relaxed payload stores -> release tag store; acquire tag poll -> payload loads.
// Parity double-buffer: slot rewritten only 2 steps later (all pollers passed).
//
// Distance (bit-exact vs harness reference, proven r9):
//   d = fma(dz,dz, fma(dx,dx, dy*dy)), dy^2 separately rounded; min-index ties.
//
// r9-r17 lesson (revised): per-step re-reads were L2-served; the ~5 us/step glue
// was LATENCY at 8 waves/CU. Fix: PPT=8 -> 32 array VGPRs, demand ~55 < 64 =
// budget at FULL occupancy. waves_per_eu(8,8) pins the budget -> VGPR<=64 ->
// 4 blocks/CU guaranteed resident (hang impossible; worst case = mild spill).
// Coords stay mutable (+0.0f, bit-neutral: feeds difference->square only) so
// RA treats them like dist[] (the class it provably never demotes).

__global__ __attribute__((amdgpu_flat_work_group_size(TPB, TPB)))
           __attribute__((amdgpu_waves_per_eu(8, 8)))
void fps_kernel(const float* __restrict__ inp, float* __restrict__ out,
                u64* __restrict__ slots)
{
#pragma clang fp contract(off)
    __shared__ u64 skey[TPB / 64];
    __shared__ float sq[3];

    const int bid  = blockIdx.x;
    const int b    = bid & 31;   // batch (blocks of batch b all land on XCD b%8)
    const int j    = bid >> 5;   // block-within-batch 0..31
    const int t    = threadIdx.x;
    const int lane = t & 63;
    const int wid  = t >> 6;

    const float* P  = inp + (size_t)b * NPTS * 3;
    float* outP     = out + (size_t)b * NPOINTS * 3;
    float* outIdx   = out + (size_t)NBATCH * NPOINTS * 3 + (size_t)b * NPOINTS;

    const int base = j * PPB;

    float px[PPT], py[PPT], pz[PPT], dist[PPT];   // 32 array VGPRs total
#pragma unroll
    for (int k = 0; k < PPT; ++k) {
        const int p = base + k * TPB + t;
        const float* pp = P + (size_t)p * 3;
        px[k] = pp[0]; py[k] = pp[1]; pz[k] = pp[2];
        dist[k] = 1e10f;
    }

    float qx = P[0], qy = P[1], qz = P[2];   // first selected index is 0
    if (j == 0 && t == 0) {
        outP[0] = qx; outP[1] = qy; outP[2] = qz;
        outIdx[0] = 0.0f;                    // whole d_out read back as float32
    }

    u64* myslots = slots + (size_t)b * (2 * BPB * SLOT_STRIDE);

    for (int it = 0; it < NPOINTS - 1; ++it) {
        // ---- update running min-dist, thread-local argmax (first-max, ascending gi) ----
        float m = -1.0f; int ki = 0;
#pragma unroll
        for (int k = 0; k < PPT; ++k) {
            float dx = px[k] - qx;
            float dy = py[k] - qy;
            float dz = pz[k] - qz;
            float yy = dy * dy;
            asm("" : "+v"(yy));                       // dy^2 stays separately rounded
            float d  = __builtin_fmaf(dz, dz,
                        __builtin_fmaf(dx, dx, yy));  // reference contraction shape
            float nd = fminf(dist[k], d);
            dist[k] = nd;
            if (nd > m) { m = nd; ki = k; }           // ascending k => ascending gi
            // bit-neutral mutations: coords become loop-carried-mutable ->
            // RA keeps them resident (cannot remat/sink a mutable value).
            px[k] = px[k] + 0.0f;
            py[k] = py[k] + 0.0f;
            pz[k] = pz[k] + 0.0f;
        }
        const int gi = base + ki * TPB + t;
        u64 key = ((u64)__float_as_uint(m) << 17) | (u64)(131071 - gi);

        // ---- wave butterfly reduce (max key) ----
#pragma unroll
        for (int s = 1; s < 64; s <<= 1) {
            u64 o = __shfl_xor(key, s, 64);
            if (o > key) key = o;
        }
        if (lane == 0) skey[wid] = key;
        __syncthreads();

        if (wid == 0) {
            // ---- block reduce over 8 wave keys ----
            u64 k2 = (lane < TPB / 64) ? skey[lane] : 0ull;
            u64 kk = k2;
#pragma unroll
            for (int s = 1; s < TPB / 64; s <<= 1) {
                u64 o = __shfl_xor(kk, s, 64);
                if (o > kk) kk = o;
            }
            const int par = it & 1;
            const u64 tag = (u64)(it + 1) << 49;
            if (lane == 0) {
                // publisher loads its winner's coords once; pollers get them with the poll
                const int bgi = 131071 - (int)(kk & 0x1FFFF);
                const float* qp = P + (size_t)bgi * 3;
                float wx = qp[0], wy = qp[1], wz = qp[2];
                u64* slot = &myslots[(size_t)(par * BPB + j) * SLOT_STRIDE];
                __hip_atomic_store(&slot[1],
                                   ((u64)__float_as_uint(wy) << 32) | __float_as_uint(wx),
                                   __ATOMIC_RELAXED, __HIP_MEMORY_SCOPE_AGENT);
                __hip_atomic_store(&slot[2], (u64)__float_as_uint(wz),
                                   __ATOMIC_RELAXED, __HIP_MEMORY_SCOPE_AGENT);
                __hip_atomic_store(&slot[0], tag | kk,
                                   __ATOMIC_RELEASE, __HIP_MEMORY_SCOPE_AGENT);
            }
            // ---- poll all BPB slots (one per lane) ----
            u64 tw = 0;
            bool ok = (lane >= BPB);
            int guard = 0;
            while (true) {
                if (!ok) {
                    tw = __hip_atomic_load(&myslots[(size_t)(par * BPB + lane) * SLOT_STRIDE],
                                           __ATOMIC_ACQUIRE, __HIP_MEMORY_SCOPE_AGENT);
                    ok = (tw >> 49) >= (u64)(it + 1);
                }
                if (__all((int)ok)) break;
                if (++guard > (1 << 20)) break;   // safeguard (co-residency is forced)
            }
            u64 pxy = 0, pzz = 0, k3 = 0;
            if (lane < BPB) {
                u64* slot = &myslots[(size_t)(par * BPB + lane) * SLOT_STRIDE];
                pxy = __hip_atomic_load(&slot[1], __ATOMIC_RELAXED, __HIP_MEMORY_SCOPE_AGENT);
                pzz = __hip_atomic_load(&slot[2], __ATOMIC_RELAXED, __HIP_MEMORY_SCOPE_AGENT);
                k3  = tw & ((1ull << 49) - 1);
            }
            u64 k3m = k3;
#pragma unroll
            for (int s = 1; s < BPB; s <<= 1) {
                u64 o = __shfl_xor(k3m, s, 64);
                if (o > k3m) k3m = o;
            }
            int w3 = __ffsll(__ballot(k3 == k3m && lane < BPB)) - 1;
            u64 wxy = __shfl(pxy, w3, 64);
            u64 wzz = __shfl(pzz, w3, 64);
            if (lane == 0) {
                float nqx = __uint_as_float((u32)wxy);
                float nqy = __uint_as_float((u32)(wxy >> 32));
                float nqz = __uint_as_float((u32)wzz);
                sq[0] = nqx; sq[1] = nqy; sq[2] = nqz;
                if (j == 0) {
                    float* o3 = outP + (size_t)(it + 1) * 3;
                    o3[0] = nqx; o3[1] = nqy; o3[2] = nqz;
                    outIdx[it + 1] = (float)(131071 - (int)(k3m & 0x1FFFF));
                }
            }
        }
        __syncthreads();
        qx = sq[0]; qy = sq[1]; qz = sq[2];
    }
}

extern "C" void kernel_launch(void* const* d_in, const int* in_sizes, int n_in,
                              void* d_out, int out_size, void* d_ws, size_t ws_size,
                              hipStream_t stream)
{
    const float* inp = (const float*)d_in[0];
    float* outp      = (float*)d_out;
    u64* slots       = (u64*)d_ws;

    hipMemsetAsync(d_ws, 0,
                   (size_t)NBATCH * 2 * BPB * SLOT_STRIDE * sizeof(u64), stream);

    fps_kernel<<<NBATCH * BPB, TPB, 0, stream>>>(inp, outp, slots);
}

// Round 19
// 24870.506 us; speedup vs baseline: 4.6795x; 4.6795x over previous
//
#include <hip/hip_runtime.h>
#include <stdint.h>

#define NBATCH  32
#define NPTS    131072
#define NPOINTS 4096
#define BPB     8            // blocks per batch -> grid = 256 = #CUs (1 block/CU, co-resident)
#define TPB     512          // threads per block
#define PPT     32           // points per thread = NPTS/BPB/TPB
#define PPB     (NPTS / BPB) // 16384

typedef unsigned long long u64;
typedef unsigned int u32;

// key layout: [60:49] = it+1 tag | [48:17] = f32 bits of max dist | [16:0] = 131071 - gi
// dist >= 0 -> float bits monotonic as unsigned; inverted index makes max() prefer
// the LOWEST global index on ties (argmax first-occurrence semantics).
//
// Distance (bit-exact vs harness reference, proven r9):
//   d = fma(dz,dz, fma(dx,dx, dy*dy)) with dy^2 separately rounded.
//
// r19 change vs r12 (the 19.9 ms best): ONLY the poll loop.
//  - relaxed spin loads (no per-iteration acquire: acquire emitted vmcnt(0)+
//    L1-invalidate every spin, serializing the wave). Tag monotonicity makes a
//    stale read harmless (one extra spin); __threadfence() on exit restores the
//    acquire ordering for the payload bits (key embeds everything we read).
//  - s_sleep(2) backoff (128 cyc) per spin: 32 batches x ~64 spinning lanes of
//    tight agent-scope loads congest the coherence fabric; backoff cuts probe
//    volume ~10x.

__global__ __attribute__((amdgpu_flat_work_group_size(TPB, TPB)))
           __attribute__((amdgpu_waves_per_eu(2, 2)))
void fps_kernel(const float* __restrict__ inp, float* __restrict__ out,
                u64* __restrict__ slots)
{
#pragma clang fp contract(off)
    const int bid  = blockIdx.x;
    const int b    = bid & 31;   // batch
    const int j    = bid >> 5;   // block-within-batch 0..7
    const int t    = threadIdx.x;
    const int lane = t & 63;
    const int wid  = t >> 6;

    const float* P  = inp + (size_t)b * NPTS * 3;
    float* outP     = out + (size_t)b * NPOINTS * 3;
    float* outIdx   = out + (size_t)NBATCH * NPOINTS * 3 + (size_t)b * NPOINTS;

    const int base = j * PPB;

    float px[PPT], py[PPT], pz[PPT], dist[PPT];
#pragma unroll
    for (int k = 0; k < PPT; ++k) {
        const int p = base + k * TPB + t;
        const float* pp = P + (size_t)p * 3;
        px[k] = pp[0]; py[k] = pp[1]; pz[k] = pp[2];
        asm volatile("" : "+v"(px[k]), "+v"(py[k]), "+v"(pz[k]));
        dist[k] = 1e10f;
    }

    float qx = P[0], qy = P[1], qz = P[2];   // first selected index is 0

    if (j == 0 && t == 0) {
        outP[0] = qx; outP[1] = qy; outP[2] = qz;
        outIdx[0] = 0.0f;                    // whole d_out is read back as float32
    }

    u64* myslots = slots + (size_t)b * (2 * BPB * 2);

    __shared__ u64 skey[TPB / 64];
    __shared__ float sq[3];

    for (int it = 0; it < NPOINTS - 1; ++it) {
        // ---- update running min-distances, thread-local argmax (first-max kept) ----
        float m = -1.0f; int ki = 0;
#pragma unroll
        for (int k = 0; k < PPT; ++k) {
            float dx = px[k] - qx;
            float dy = py[k] - qy;
            float dz = pz[k] - qz;
            float yy = dy * dy;
            asm("" : "+v"(yy));                       // dy^2 stays a separately-rounded mul
            float d  = __builtin_fmaf(dz, dz,
                        __builtin_fmaf(dx, dx, yy));  // reference contraction shape
            float nd = fminf(dist[k], d);
            dist[k] = nd;
            if (nd > m) { m = nd; ki = k; }           // ascending k => ascending gi (first max)
        }
        const int gi = base + ki * TPB + t;
        u64 key = ((u64)__float_as_uint(m) << 17) | (u64)(131071 - gi);

        // ---- wave butterfly reduce (max key) ----
#pragma unroll
        for (int s = 1; s < 64; s <<= 1) {
            u64 o = __shfl_xor(key, s, 64);
            if (o > key) key = o;
        }
        if (lane == 0) skey[wid] = key;
        __syncthreads();

        if (wid == 0) {
            u64 k2 = (lane < TPB / 64) ? skey[lane] : 0ull;
#pragma unroll
            for (int s = 1; s < TPB / 64; s <<= 1) {
                u64 o = __shfl_xor(k2, s, 64);
                if (o > k2) k2 = o;
            }
            const int par = it & 1;
            const u64 tag = (u64)(it + 1) << 49;
            if (lane == 0) {
                __hip_atomic_store(&myslots[(par * BPB + j) * 2], tag | k2,
                                   __ATOMIC_RELEASE, __HIP_MEMORY_SCOPE_AGENT);
            }
            // ---- poll: relaxed spin + s_sleep backoff, acquire fence on exit ----
            u64 v = 0;
            bool ok = (lane >= BPB);
            int guard = 0;
            while (true) {
                if (!ok) {
                    v = __hip_atomic_load(&myslots[(par * BPB + lane) * 2 + 0],
                                          __ATOMIC_RELAXED, __HIP_MEMORY_SCOPE_AGENT);
                    ok = (v >> 49) >= (u64)(it + 1);
                }
                if (__all((int)ok)) break;
                if (++guard > (1 << 18)) break;       // hang safeguard
                __builtin_amdgcn_s_sleep(2);          // 128-cycle backoff
            }
            __threadfence();                          // acquire ordering on exit
            u64 k3 = (lane < BPB) ? (v & ((1ull << 49) - 1)) : 0ull;
#pragma unroll
            for (int s = 1; s < BPB; s <<= 1) {
                u64 o = __shfl_xor(k3, s, 64);
                if (o > k3) k3 = o;
            }
            const int wgi = 131071 - (int)(k3 & 0x1FFFF);
            if (lane == 0) {
                const float* qp = P + (size_t)wgi * 3;
                float nqx = qp[0], nqy = qp[1], nqz = qp[2];
                sq[0] = nqx; sq[1] = nqy; sq[2] = nqz;
                if (j == 0) {
                    float* o3 = outP + (size_t)(it + 1) * 3;
                    o3[0] = nqx; o3[1] = nqy; o3[2] = nqz;
                    outIdx[it + 1] = (float)wgi;
                }
            }
        }
        __syncthreads();
        qx = sq[0]; qy = sq[1]; qz = sq[2];
    }
}

extern "C" void kernel_launch(void* const* d_in, const int* in_sizes, int n_in,
                              void* d_out, int out_size, void* d_ws, size_t ws_size,
                              hipStream_t stream)
{
    const float* inp = (const float*)d_in[0];
    float* outp      = (float*)d_out;
    u64* slots       = (u64*)d_ws;

    hipMemsetAsync(d_ws, 0, (size_t)NBATCH * 2 * BPB * 2 * sizeof(u64), stream);

    fps_kernel<<<NBATCH * BPB, TPB, 0, stream>>>(inp, outp, slots);
}

// Round 20
// 21553.882 us; speedup vs baseline: 5.3995x; 1.1539x over previous
//
#include <hip/hip_runtime.h>
#include <stdint.h>

#define NBATCH  32
#define NPTS    131072
#define NPOINTS 4096
#define BPB     8            // blocks per batch -> grid = 256 = #CUs (1 block/CU via 128 KB LDS)
#define TPB     1024         // 16 waves/block = 4 waves/SIMD (2x the hiding of all prior rounds)
#define PPT     16           // points per thread = NPTS/BPB/TPB
#define PPB     (NPTS / BPB) // 16384 points per block

typedef unsigned long long u64;
typedef unsigned int u32;

// key layout: [60:49] = it+1 tag | [48:17] = f32 bits of max dist | [16:0] = 131071 - gi
// dist >= 0 -> float bits monotonic; inverted index -> max() prefers LOWEST gi on ties.
//
// Distance (bit-exact vs harness reference, proven r9):
//   d = fma(dz,dz, fma(dx,dx, dy*dy)) with dy^2 separately rounded.
//
// Structure (r9-r19 lessons):
//  - x,y in 128 KB STATIC LDS (static informs the occupancy model -> RA budget is
//    computed for 1 block/CU; r13's dynamic-LDS hid it and everything spilled).
//  - z, dist: mutable register arrays (the only class RA provably keeps resident);
//    pz mutated bit-neutrally (+0.0f feeds difference->square only).
//  - PPT=16 keeps demand ~55 VGPR << 128 budget -> no r17-style 1-reg spill.
//  - Sync: r12's lean protocol (1-word slots, acquire spin, NO sleep - r19 showed
//    sleep costs ~1 quantum per step). Post-detect winner load is L2-local-hot:
//    all 8 blocks of a batch live on XCD b%8 and the owner just touched the line.

__global__ __attribute__((amdgpu_flat_work_group_size(TPB, TPB)))
void fps_kernel(const float* __restrict__ inp, float* __restrict__ out,
                u64* __restrict__ slots)
{
#pragma clang fp contract(off)
    __shared__ float2 XY[PPB];       // 128 KB static LDS
    __shared__ u64 skey[TPB / 64];   // 16 wave winners
    __shared__ float sq[3];

    const int bid  = blockIdx.x;
    const int b    = bid & 31;   // batch (all 8 blocks of batch b -> XCD b%8)
    const int j    = bid >> 5;   // block-within-batch 0..7
    const int t    = threadIdx.x;
    const int lane = t & 63;
    const int wid  = t >> 6;

    const float* P  = inp + (size_t)b * NPTS * 3;
    float* outP     = out + (size_t)b * NPOINTS * 3;
    float* outIdx   = out + (size_t)NBATCH * NPOINTS * 3 + (size_t)b * NPOINTS;

    const int base = j * PPB;

    float pz[PPT], dist[PPT];    // 32 mutable VGPRs
#pragma unroll
    for (int k = 0; k < PPT; ++k) {
        const int l = k * TPB + t;
        const float* pp = P + (size_t)(base + l) * 3;
        float x = pp[0], y = pp[1], z = pp[2];
        XY[l] = make_float2(x, y);
        pz[k] = z;
        dist[k] = 1e10f;
    }

    float qx = P[0], qy = P[1], qz = P[2];   // first selected index is 0
    if (j == 0 && t == 0) {
        outP[0] = qx; outP[1] = qy; outP[2] = qz;
        outIdx[0] = 0.0f;                    // whole d_out read back as float32
    }

    u64* myslots = slots + (size_t)b * (2 * BPB * 2);

    __syncthreads();   // XY visible to all waves

    for (int it = 0; it < NPOINTS - 1; ++it) {
        // ---- update running min-dist, thread-local argmax (first-max, ascending gi) ----
        float m = -1.0f; int ki = 0;
#pragma unroll
        for (int k = 0; k < PPT; ++k) {
            float2 xy = XY[k * TPB + t];              // ds_read_b64, 2-way alias (free)
            float dx = xy.x - qx;
            float dy = xy.y - qy;
            float dz = pz[k] - qz;
            float yy = dy * dy;
            asm("" : "+v"(yy));                       // dy^2 stays separately rounded
            float d  = __builtin_fmaf(dz, dz,
                        __builtin_fmaf(dx, dx, yy));  // reference contraction shape
            float nd = fminf(dist[k], d);
            dist[k] = nd;
            if (nd > m) { m = nd; ki = k; }           // ascending k => ascending gi
            pz[k] = pz[k] + 0.0f;  // bit-neutral: pz loop-carried-mutable -> resident
        }
        const int gi = base + ki * TPB + t;
        u64 key = ((u64)__float_as_uint(m) << 17) | (u64)(131071 - gi);

        // ---- wave butterfly reduce (max key) ----
#pragma unroll
        for (int s = 1; s < 64; s <<= 1) {
            u64 o = __shfl_xor(key, s, 64);
            if (o > key) key = o;
        }
        if (lane == 0) skey[wid] = key;
        __syncthreads();

        if (wid == 0) {
            // ---- block reduce over 16 wave keys ----
            u64 k2 = (lane < TPB / 64) ? skey[lane] : 0ull;
#pragma unroll
            for (int s = 1; s < TPB / 64; s <<= 1) {
                u64 o = __shfl_xor(k2, s, 64);
                if (o > k2) k2 = o;
            }
            const int par = it & 1;
            const u64 tag = (u64)(it + 1) << 49;
            if (lane == 0) {
                __hip_atomic_store(&myslots[(par * BPB + j) * 2], tag | k2,
                                   __ATOMIC_RELEASE, __HIP_MEMORY_SCOPE_AGENT);
            }
            // ---- poll the 8 slots (acquire spin, r12-proven) ----
            u64 v = 0;
            bool ok = (lane >= BPB);
            int guard = 0;
            while (true) {
                if (!ok) {
                    v = __hip_atomic_load(&myslots[(par * BPB + lane) * 2 + 0],
                                          __ATOMIC_ACQUIRE, __HIP_MEMORY_SCOPE_AGENT);
                    ok = (v >> 49) >= (u64)(it + 1);
                }
                if (__all((int)ok)) break;
                if (++guard > (1 << 20)) break;   // hang safeguard (co-resident by LDS cap)
            }
            u64 k3 = (lane < BPB) ? (v & ((1ull << 49) - 1)) : 0ull;
#pragma unroll
            for (int s = 1; s < BPB; s <<= 1) {
                u64 o = __shfl_xor(k3, s, 64);
                if (o > k3) k3 = o;
            }
            const int wgi = 131071 - (int)(k3 & 0x1FFFF);
            if (lane == 0) {
                const float* qp = P + (size_t)wgi * 3;   // L2-local-hot (same-XCD owner)
                float nqx = qp[0], nqy = qp[1], nqz = qp[2];
                sq[0] = nqx; sq[1] = nqy; sq[2] = nqz;
                if (j == 0) {
                    float* o3 = outP + (size_t)(it + 1) * 3;
                    o3[0] = nqx; o3[1] = nqy; o3[2] = nqz;
                    outIdx[it + 1] = (float)wgi;
                }
            }
        }
        __syncthreads();
        qx = sq[0]; qy = sq[1]; qz = sq[2];
    }
}

extern "C" void kernel_launch(void* const* d_in, const int* in_sizes, int n_in,
                              void* d_out, int out_size, void* d_ws, size_t ws_size,
                              hipStream_t stream)
{
    const float* inp = (const float*)d_in[0];
    float* outp      = (float*)d_out;
    u64* slots       = (u64*)d_ws;

    hipMemsetAsync(d_ws, 0, (size_t)NBATCH * 2 * BPB * 2 * sizeof(u64), stream);

    fps_kernel<<<NBATCH * BPB, TPB, 0, stream>>>(inp, outp, slots);
}